// Round 2
// baseline (584.292 us; speedup 1.0000x reference)
//
#include <hip/hip_runtime.h>
#include <math.h>

// SSIM-with-logits fused kernel for MI355X (gfx950). Round 2.
// Changes vs R1: TILE_H 128->32 (grid 512->2048, occupancy was the limiter),
// mod-11 accumulator slots with fully-unrolled 11-row groups (removes the
// 50 mov/row register shift), float2-interleaved LDS (ds_read_b64, halves
// LDS instruction count).

#define H_IMG 1024
#define W_IMG 1024
#define N_IMG 16
#define TILE_W 256
#define TILE_H 32
#define PADR 5
#define LDS_S2 268  // float2 stride per staged row (>= 266)

// Normalized 1D Gaussian, WS=11, sigma=1.5 (validated absmax=0 in R1)
constexpr float GW[11] = {
    0.00102838f, 0.00759877f, 0.03600077f, 0.10936069f, 0.21300553f,
    0.26601172f,
    0.21300553f, 0.10936069f, 0.03600077f, 0.00759877f, 0.00102838f};

__device__ __forceinline__ int reflect_i(int i, int n) {
    i = (i < 0) ? -i : i;
    i = (i >= n) ? (2 * n - 2 - i) : i;
    return i;
}

__device__ __forceinline__ void ssim_emit(
    float mu1, float mu2, float e11, float e22, float e12, float& loss_sum)
{
    const float mu1s = mu1 * mu1;
    const float mu2s = mu2 * mu2;
    const float mu12 = mu1 * mu2;
    const float s1  = e11 - mu1s;
    const float s2  = e22 - mu2s;
    const float s12 = e12 - mu12;
    const float C1 = 1e-4f, C2 = 9e-4f;
    const float num = (2.0f * mu12 + C1) * (2.0f * s12 + C2);
    const float den = (mu1s + mu2s + C1) * (s1 + s2 + C2);
    float l = 1.0f - num / den;
    l = fminf(fmaxf(l, 0.0f), 1.0f) * 0.5f;
    loss_sum += l;
}

// Stage NR rows starting at group base gb (input row y_start+gb+r) into LDS
template<int NR>
__device__ __forceinline__ void stage_rows(
    float2 (&ab)[11][LDS_S2], const float* __restrict__ A,
    const float* __restrict__ B, int y_start, int gb, int tid, int c0, int c1)
{
#pragma unroll
    for (int r = 0; r < NR; ++r) {
        const int yy = reflect_i(y_start + gb + r, H_IMG);
        const float* __restrict__ ar = A + (size_t)yy * W_IMG;
        const float* __restrict__ br = B + (size_t)yy * W_IMG;
        const float av = ar[c0];
        const float bv = br[c0];
        ab[r][tid] = make_float2(1.0f / (1.0f + __expf(-av)), bv);
        if (tid < 2 * PADR) {
            const float av2 = ar[c1];
            const float bv2 = br[c1];
            ab[r][TILE_W + tid] = make_float2(1.0f / (1.0f + __expf(-av2)), bv2);
        }
    }
}

// Process NR staged rows. Group base is >= 11 when GUARD==false (middle/tail
// groups: every row completes an output; out-of-range accumulation for rows
// past output 31 lands in already-reset, never-re-read slots — provably
// safe since pollution for slot s begins exactly one row after s's reset).
// GUARD==true is the B==0 group: skip j>r (would-be negative output rows);
// only r==10 completes an output (o=0).
template<int NR, bool GUARD>
__device__ __forceinline__ void process_group(
    const float2 (&ab)[11][LDS_S2], int tid,
    float (&aA)[11], float (&aB)[11], float (&aAA)[11],
    float (&aBB)[11], float (&aAB)[11], float& loss_sum)
{
#pragma unroll
    for (int r = 0; r < NR; ++r) {
        // ---- horizontal 11-tap of 5 channels ----
        float ha = 0.f, hb = 0.f, haa = 0.f, hbb = 0.f, hab = 0.f;
#pragma unroll
        for (int k = 0; k < 11; ++k) {
            const float2 v = ab[r][tid + k];
            const float wa = GW[k] * v.x;
            const float wb = GW[k] * v.y;
            ha += wa;
            hb += wb;
            haa = fmaf(wa, v.x, haa);
            hab = fmaf(wa, v.y, hab);
            hbb = fmaf(wb, v.y, hbb);
        }
        // ---- vertical scatter into mod-11 slots (all indices fold) ----
#pragma unroll
        for (int j = 0; j < 11; ++j) {
            if (!(GUARD && j > r)) {
                const int s = (r - j + 22) % 11;
                const float w = GW[j];
                aA[s]  = fmaf(w, ha,  aA[s]);
                aB[s]  = fmaf(w, hb,  aB[s]);
                aAA[s] = fmaf(w, haa, aAA[s]);
                aBB[s] = fmaf(w, hbb, aBB[s]);
                aAB[s] = fmaf(w, hab, aAB[s]);
            }
        }
        // ---- completion: slot (r+1)%11 finished an output row ----
        if (!GUARD || r == 10) {
            const int s = (r + 1) % 11;
            ssim_emit(aA[s], aB[s], aAA[s], aBB[s], aAB[s], loss_sum);
            aA[s] = 0.f; aB[s] = 0.f; aAA[s] = 0.f; aBB[s] = 0.f; aAB[s] = 0.f;
        }
    }
}

__global__ __launch_bounds__(256, 5) void ssim_main(
    const float* __restrict__ inp, const float* __restrict__ tgt,
    float* __restrict__ out)
{
    __shared__ float2 ab_s[11][LDS_S2];
    __shared__ float red[4];

    const int tid = threadIdx.x;
    const int blk = blockIdx.x;
    const int b   = blk >> 7;           // image 0..15
    const int rem = blk & 127;
    const int cx  = rem & 3;            // column tile 0..3
    const int ry  = rem >> 2;           // row band 0..31
    const int x0  = cx * TILE_W;
    const int y0  = ry * TILE_H;

    const float* __restrict__ A = inp + (size_t)b * (H_IMG * (size_t)W_IMG);
    const float* __restrict__ B = tgt + (size_t)b * (H_IMG * (size_t)W_IMG);

    const int c0 = reflect_i(x0 - PADR + tid, W_IMG);
    const int c1 = (tid < 2 * PADR) ? reflect_i(x0 + TILE_W - PADR + tid, W_IMG) : 0;

    float aA[11], aB[11], aAA[11], aBB[11], aAB[11];
#pragma unroll
    for (int j = 0; j < 11; ++j) {
        aA[j] = 0.f; aB[j] = 0.f; aAA[j] = 0.f; aBB[j] = 0.f; aAB[j] = 0.f;
    }
    float loss_sum = 0.0f;

    const int y_start = y0 - PADR;  // 42 input rows: groups 11,11,11,9

    // group 0: rows 0..10 (guarded low edge, one completion)
    stage_rows<11>(ab_s, A, B, y_start, 0, tid, c0, c1);
    __syncthreads();
    process_group<11, true>(ab_s, tid, aA, aB, aAA, aBB, aAB, loss_sum);

    // middle groups: rows 11..21, 22..32 — shared unrolled body
    for (int gb = 11; gb <= 22; gb += 11) {
        __syncthreads();
        stage_rows<11>(ab_s, A, B, y_start, gb, tid, c0, c1);
        __syncthreads();
        process_group<11, false>(ab_s, tid, aA, aB, aAA, aBB, aAB, loss_sum);
    }

    // tail group: rows 33..41 (9 rows)
    __syncthreads();
    stage_rows<9>(ab_s, A, B, y_start, 33, tid, c0, c1);
    __syncthreads();
    process_group<9, false>(ab_s, tid, aA, aB, aAA, aBB, aAB, loss_sum);

    // ---- reduction: wave64 shuffle -> LDS across 4 waves -> atomicAdd ----
#pragma unroll
    for (int off = 32; off > 0; off >>= 1)
        loss_sum += __shfl_down(loss_sum, off, 64);
    const int wave = tid >> 6;
    if ((tid & 63) == 0) red[wave] = loss_sum;
    __syncthreads();
    if (tid == 0) {
        const float s = red[0] + red[1] + red[2] + red[3];
        atomicAdd(out, s * (1.0f / ((float)N_IMG * H_IMG * W_IMG)));
    }
}

extern "C" void kernel_launch(void* const* d_in, const int* in_sizes, int n_in,
                              void* d_out, int out_size, void* d_ws, size_t ws_size,
                              hipStream_t stream) {
    const float* inp = (const float*)d_in[0];
    const float* tgt = (const float*)d_in[1];
    float* out = (float*)d_out;

    // d_out is poisoned 0xAA before every launch; zero it for the atomic sum.
    hipMemsetAsync(out, 0, sizeof(float), stream);

    const int grid = N_IMG * 4 * (H_IMG / TILE_H);  // 2048 blocks
    ssim_main<<<grid, 256, 0, stream>>>(inp, tgt, out);
}